// Round 3
// baseline (799.705 us; speedup 1.0000x reference)
//
#include <hip/hip_runtime.h>
#include <hip/hip_bf16.h>
#include <math.h>

#define H_ 16
#define LQ_ 2048
#define LK_ 2048
#define D_ 64
#define MBLK_ 32                 // q-rows per block
#define NWAVE_ 4
#define STRIP_ (LK_ / NWAVE_)    // 512 k-cols per wave (k-split)
#define NCH_ (STRIP_ / 32)       // 16 chunks of 32 k-cols

using bf16x8  = __attribute__((ext_vector_type(8))) short;
using floatx4 = __attribute__((ext_vector_type(4))) float;

__device__ __forceinline__ unsigned short f2bf(float x) {
  unsigned u = __builtin_bit_cast(unsigned, x);
  return (unsigned short)((u + 0x7fffu + ((u >> 16) & 1u)) >> 16);
}
__device__ __forceinline__ float bf2f(unsigned short b) {
  return __builtin_bit_cast(float, ((unsigned)b) << 16);
}
__device__ __forceinline__ void hilo8(const float* __restrict__ x, bf16x8& hv, bf16x8& lv) {
#pragma unroll
  for (int j = 0; j < 8; ++j) {
    unsigned short hb = f2bf(x[j]);
    float d = x[j] - bf2f(hb);
    hv[j] = (short)hb;
    lv[j] = (short)(unsigned short)(__builtin_bit_cast(unsigned, d) >> 16);
  }
}

__global__ void detect_mask_kernel(const unsigned int* __restrict__ m,
                                   int* __restrict__ flag) {
  if (threadIdx.x == 0) {
    unsigned int acc = 0u;
#pragma unroll 8
    for (int i = 0; i < 256; ++i) acc |= m[i];
    *flag = (acc & 0xFFFFFF00u) ? 1 : 0;
  }
}

__global__ __launch_bounds__(256, 2)
void attn_mfma_kernel(const float* __restrict__ Qg, const float* __restrict__ Kg,
                      const float* __restrict__ Vg, const void* __restrict__ Mg,
                      const int* __restrict__ flagp,
                      float* __restrict__ Og, float* __restrict__ Ag) {
  const int tid = (int)threadIdx.x;
  const int l   = tid & 63;
  const int w   = tid >> 6;
  const int lm  = l & 15;
  const int lg  = l >> 4;
  const int hd  = (int)blockIdx.y;
  const int q0  = (int)blockIdx.x * MBLK_;
  const int k0w = w * STRIP_;

  __shared__ __align__(16) float OM[NWAVE_][MBLK_ * D_];
  __shared__ float Stats[NWAVE_][MBLK_][2];

  short* Pw = reinterpret_cast<short*>(&OM[0][0]) + w * 2048;
  short* Ph = Pw;
  short* Pl = Pw + 1024;

  const int maskByte = *flagp;
  const unsigned char* Mb = (const unsigned char*)Mg;
  const int* Mi = (const int*)Mg;

  const float* Qh_ = Qg + (size_t)hd * LQ_ * D_;
  const float* Kh_ = Kg + (size_t)hd * LK_ * D_;

  bf16x8 qh[2][2], ql[2][2];
#pragma unroll
  for (int Mt = 0; Mt < 2; ++Mt) {
    const float* qp = Qh_ + (size_t)(q0 + Mt * 16 + lm) * D_;
#pragma unroll
    for (int s = 0; s < 2; ++s) {
      float x[8];
      *(floatx4*)(x)     = *(const floatx4*)(qp + s * 32 + lg * 8);
      *(floatx4*)(x + 4) = *(const floatx4*)(qp + s * 32 + lg * 8 + 4);
      hilo8(x, qh[Mt][s], ql[Mt][s]);
    }
  }

  float mreg[8], sreg[8];
#pragma unroll
  for (int i = 0; i < 8; ++i) { mreg[i] = -1e30f; sreg[i] = 0.0f; }

#pragma unroll 1
  for (int c = 0; c < NCH_; ++c) {
#pragma unroll
    for (int kt = 0; kt < 2; ++kt) {
      const int kcol = k0w + c * 32 + kt * 16 + lm;
      const float* kp = Kh_ + (size_t)kcol * D_;
      bf16x8 kh[2], kl[2];
#pragma unroll
      for (int s = 0; s < 2; ++s) {
        float x[8];
        *(floatx4*)(x)     = *(const floatx4*)(kp + s * 32 + lg * 8);
        *(floatx4*)(x + 4) = *(const floatx4*)(kp + s * 32 + lg * 8 + 4);
        hilo8(x, kh[s], kl[s]);
      }
#pragma unroll
      for (int Mt = 0; Mt < 2; ++Mt) {
        floatx4 acc = {0.f, 0.f, 0.f, 0.f};
#pragma unroll
        for (int s = 0; s < 2; ++s) {
          acc = __builtin_amdgcn_mfma_f32_16x16x32_bf16(qh[Mt][s], kh[s], acc, 0, 0, 0);
          acc = __builtin_amdgcn_mfma_f32_16x16x32_bf16(ql[Mt][s], kh[s], acc, 0, 0, 0);
          acc = __builtin_amdgcn_mfma_f32_16x16x32_bf16(qh[Mt][s], kl[s], acc, 0, 0, 0);
        }
#pragma unroll
        for (int j = 0; j < 4; ++j) {
          const int row = Mt * 16 + lg * 4 + j;
          const size_t mi = ((size_t)hd * LQ_ + q0 + row) * (size_t)LK_ + kcol;
          const int msk = maskByte ? (int)Mb[mi] : Mi[mi];
          const float sv = msk ? -1e30f : acc[j] * 0.125f;
          const int rs = Mt * 4 + j;
          const float mo = mreg[rs];
          const float mn = fmaxf(mo, sv);
          sreg[rs] = sreg[rs] * __expf(mo - mn) + (msk ? 0.0f : __expf(sv - mn));
          mreg[rs] = mn;
        }
      }
    }
  }

#pragma unroll
  for (int rs = 0; rs < 8; ++rs) {
    float m = mreg[rs], S = sreg[rs];
#pragma unroll
    for (int off = 1; off <= 8; off <<= 1) {
      float mo = __shfl_xor(m, off, 64);
      float So = __shfl_xor(S, off, 64);
      float mn = fmaxf(m, mo);
      S = S * __expf(m - mn) + So * __expf(mo - mn);
      m = mn;
    }
    mreg[rs] = m; sreg[rs] = S;
  }
  if (lm == 0) {
#pragma unroll
    for (int rs = 0; rs < 8; ++rs) {
      const int row = (rs >> 2) * 16 + lg * 4 + (rs & 3);
      Stats[w][row][0] = mreg[rs];
      Stats[w][row][1] = sreg[rs];
    }
  }
  __syncthreads();
  float mfin[8], isum[8];
#pragma unroll
  for (int rs = 0; rs < 8; ++rs) {
    const int row = (rs >> 2) * 16 + lg * 4 + (rs & 3);
    float m = Stats[0][row][0], S = Stats[0][row][1];
#pragma unroll
    for (int ww = 1; ww < NWAVE_; ++ww) {
      float mo = Stats[ww][row][0], So = Stats[ww][row][1];
      float mn = fmaxf(m, mo);
      S = S * __expf(m - mn) + So * __expf(mo - mn);
      m = mn;
    }
    mfin[rs] = m; isum[rs] = 1.0f / S;
  }

  floatx4 oacc[2][4];
#pragma unroll
  for (int Mt = 0; Mt < 2; ++Mt)
#pragma unroll
    for (int Nt = 0; Nt < 4; ++Nt) oacc[Mt][Nt] = {0.f, 0.f, 0.f, 0.f};

#pragma unroll 1
  for (int c = 0; c < NCH_; ++c) {
    const int kc0 = k0w + c * 32;
#pragma unroll
    for (int kt = 0; kt < 2; ++kt) {
      const int kcol = kc0 + kt * 16 + lm;
      const float* kp = Kh_ + (size_t)kcol * D_;
      bf16x8 kh[2], kl[2];
#pragma unroll
      for (int s = 0; s < 2; ++s) {
        float x[8];
        *(floatx4*)(x)     = *(const floatx4*)(kp + s * 32 + lg * 8);
        *(floatx4*)(x + 4) = *(const floatx4*)(kp + s * 32 + lg * 8 + 4);
        hilo8(x, kh[s], kl[s]);
      }
#pragma unroll
      for (int Mt = 0; Mt < 2; ++Mt) {
        floatx4 acc = {0.f, 0.f, 0.f, 0.f};
#pragma unroll
        for (int s = 0; s < 2; ++s) {
          acc = __builtin_amdgcn_mfma_f32_16x16x32_bf16(qh[Mt][s], kh[s], acc, 0, 0, 0);
          acc = __builtin_amdgcn_mfma_f32_16x16x32_bf16(ql[Mt][s], kh[s], acc, 0, 0, 0);
          acc = __builtin_amdgcn_mfma_f32_16x16x32_bf16(qh[Mt][s], kl[s], acc, 0, 0, 0);
        }
#pragma unroll
        for (int j = 0; j < 4; ++j) {
          const int row = Mt * 16 + lg * 4 + j;
          const size_t mi = ((size_t)hd * LQ_ + q0 + row) * (size_t)LK_ + kcol;
          const int msk = maskByte ? (int)Mb[mi] : Mi[mi];
          const int rs = Mt * 4 + j;
          const float p = msk ? 0.0f : __expf(acc[j] * 0.125f - mfin[rs]) * isum[rs];
          Ag[mi] = p;
          const unsigned short phb = f2bf(p);
          Ph[row * 32 + kt * 16 + lm] = (short)phb;
          Pl[row * 32 + kt * 16 + lm] =
              (short)(unsigned short)(__builtin_bit_cast(unsigned, p - bf2f(phb)) >> 16);
        }
      }
    }
    bf16x8 pa[2], plo[2];
#pragma unroll
    for (int Mt = 0; Mt < 2; ++Mt) {
      pa[Mt]  = *(const bf16x8*)(Ph + (Mt * 16 + lm) * 32 + lg * 8);
      plo[Mt] = *(const bf16x8*)(Pl + (Mt * 16 + lm) * 32 + lg * 8);
    }
#pragma unroll
    for (int Nt = 0; Nt < 4; ++Nt) {
      float vx[8];
#pragma unroll
      for (int jj = 0; jj < 8; ++jj)
        vx[jj] = Vg[(size_t)(kc0 + lg * 8 + jj) * D_ + Nt * 16 + lm];
      bf16x8 vh, vl;
      hilo8(vx, vh, vl);
#pragma unroll
      for (int Mt = 0; Mt < 2; ++Mt) {
        floatx4 o = oacc[Mt][Nt];
        o = __builtin_amdgcn_mfma_f32_16x16x32_bf16(pa[Mt],  vh, o, 0, 0, 0);
        o = __builtin_amdgcn_mfma_f32_16x16x32_bf16(plo[Mt], vh, o, 0, 0, 0);
        o = __builtin_amdgcn_mfma_f32_16x16x32_bf16(pa[Mt],  vl, o, 0, 0, 0);
        oacc[Mt][Nt] = o;
      }
    }
  }

  __syncthreads();
#pragma unroll
  for (int Mt = 0; Mt < 2; ++Mt)
#pragma unroll
    for (int Nt = 0; Nt < 4; ++Nt)
#pragma unroll
      for (int j = 0; j < 4; ++j)
        OM[w][(Mt * 16 + lg * 4 + j) * D_ + Nt * 16 + lm] = oacc[Mt][Nt][j];
  __syncthreads();
  for (int i = tid; i < MBLK_ * D_; i += 256) {
    const float s0 = OM[0][i] + OM[1][i] + OM[2][i] + OM[3][i];
    Og[((size_t)hd * LQ_ + q0 + (i >> 6)) * D_ + (i & 63)] = s0;
  }
}

extern "C" void kernel_launch(void* const* d_in, const int* in_sizes, int n_in,
                              void* d_out, int out_size, void* d_ws, size_t ws_size,
                              hipStream_t stream) {
  const float* Qg = (const float*)d_in[0];
  const float* Kg = (const float*)d_in[1];
  const float* Vg = (const float*)d_in[2];
  const void*  Mg = d_in[3];
  int* flag = (int*)d_ws;

  hipLaunchKernelGGL(detect_mask_kernel, dim3(1), dim3(64), 0, stream,
                     (const unsigned int*)Mg, flag);

  float* Og = (float*)d_out;                               // (H, LQ, DV)
  float* Ag = (float*)d_out + (size_t)H_ * LQ_ * D_;       // (H, LQ, LK)

  dim3 grid(LQ_ / MBLK_, H_);
  hipLaunchKernelGGL(attn_mfma_kernel, grid, dim3(256), 0, stream,
                     Qg, Kg, Vg, Mg, flag, Og, Ag);
}

// Round 4
// 691.858 us; speedup vs baseline: 1.1559x; 1.1559x over previous
//
#include <hip/hip_runtime.h>
#include <hip/hip_bf16.h>
#include <math.h>

#define H_ 16
#define LQ_ 2048
#define LK_ 2048
#define D_ 64
#define QB_ 16                 // q rows per block
#define NW_ 4                  // waves per block (k-split)
#define STRIP_ (LK_ / NW_)     // 512 cols per wave
#define NTL_ (STRIP_ / 16)     // 32 col-tiles of 16
#define NCH_ (STRIP_ / 32)     // 16 chunks of 32 (PV k-steps)
#define PP_ 40                 // P LDS pitch in shorts (80 B: rows 16B-aligned)

using bf16x8  = __attribute__((ext_vector_type(8))) short;
using floatx4 = __attribute__((ext_vector_type(4))) float;

__device__ __forceinline__ unsigned short f2bf(float x) {
  unsigned u = __builtin_bit_cast(unsigned, x);
  return (unsigned short)((u + 0x7fffu + ((u >> 16) & 1u)) >> 16);
}
__device__ __forceinline__ float bf2f(unsigned short b) {
  return __builtin_bit_cast(float, ((unsigned)b) << 16);
}
__device__ __forceinline__ void hilo8(const float* __restrict__ x, bf16x8& hv, bf16x8& lv) {
#pragma unroll
  for (int j = 0; j < 8; ++j) {
    unsigned short hb = f2bf(x[j]);
    float d = x[j] - bf2f(hb);
    hv[j] = (short)hb;
    lv[j] = (short)(unsigned short)(__builtin_bit_cast(unsigned, d) >> 16);
  }
}

// ---- mask dtype detect: int32 0/1 words never have nonzero high bytes ----
__global__ void detect_mask_kernel(const unsigned* __restrict__ m, int* __restrict__ flag) {
  const int l = (int)threadIdx.x;  // 64 threads
  unsigned acc = 0;
#pragma unroll
  for (int i = 0; i < 4; ++i) acc |= m[l * 4 + i];
  unsigned long long any = __ballot(acc & 0xFFFFFF00u);
  if (l == 0) *flag = any ? 1 : 0;
}

// ---- bitpack mask: bool(1B) or int32 -> 1 bit per element, word = 32 cols ----
__global__ void pack_mask_kernel(const void* __restrict__ Mg, const int* __restrict__ flagp,
                                 unsigned* __restrict__ Wp) {
  const size_t i = (size_t)blockIdx.x * 256 + threadIdx.x;  // 2,097,152 words
  unsigned wbits = 0;
  if (*flagp) {
    const uint4* p = (const uint4*)((const unsigned char*)Mg + i * 32);
    uint4 a = p[0], b = p[1];
    unsigned v[8] = {a.x, a.y, a.z, a.w, b.x, b.y, b.z, b.w};
#pragma unroll
    for (int k = 0; k < 8; ++k)
#pragma unroll
      for (int bb = 0; bb < 4; ++bb)
        wbits |= (((v[k] >> (8 * bb)) & 0xFFu) ? 1u : 0u) << (4 * k + bb);
  } else {
    const uint4* p = (const uint4*)((const int*)Mg + i * 32);
#pragma unroll
    for (int k = 0; k < 8; ++k) {
      uint4 a = p[k];
      wbits |= (a.x ? 1u : 0u) << (4 * k)     | (a.y ? 1u : 0u) << (4 * k + 1) |
               (a.z ? 1u : 0u) << (4 * k + 2) | (a.w ? 1u : 0u) << (4 * k + 3);
    }
  }
  Wp[i] = wbits;
}

// ---- fp32 -> bf16 hi/lo planes (Q, K), row-major preserved ----
__global__ void conv_hilo_kernel(const float* __restrict__ X,
                                 unsigned short* __restrict__ Hh,
                                 unsigned short* __restrict__ Hl) {
  const size_t i = (size_t)blockIdx.x * 256 + threadIdx.x;  // 262,144 threads x 8 elems
  float x[8];
  *(floatx4*)x       = *(const floatx4*)(X + i * 8);
  *(floatx4*)(x + 4) = *(const floatx4*)(X + i * 8 + 4);
  bf16x8 hv, lv;
  hilo8(x, hv, lv);
  *(bf16x8*)(Hh + i * 8) = hv;
  *(bf16x8*)(Hl + i * 8) = lv;
}

// ---- V (LK,DV) -> transposed bf16 hi/lo planes (DV rows of LK) ----
__global__ void conv_vt_kernel(const float* __restrict__ V,
                               unsigned short* __restrict__ Th,
                               unsigned short* __restrict__ Tl) {
  const int i = (int)(blockIdx.x * 256 + threadIdx.x);  // 131,072
  const int d = i >> 11, k = i & 2047;
  float x = V[(size_t)k * D_ + d];
  unsigned short hb = f2bf(x);
  float rem = x - bf2f(hb);
  Th[(size_t)d * LK_ + k] = hb;
  Tl[(size_t)d * LK_ + k] = (unsigned short)(__builtin_bit_cast(unsigned, rem) >> 16);
}

template <bool PRE>
__global__ __launch_bounds__(256, 2)
void attn_sp_kernel(const float* __restrict__ Qg, const float* __restrict__ Kg,
                    const float* __restrict__ Vg, const void* __restrict__ Mg,
                    const int* __restrict__ flagp,
                    const unsigned* __restrict__ Wp,
                    const unsigned short* __restrict__ Qhp, const unsigned short* __restrict__ Qlp,
                    const unsigned short* __restrict__ Khp, const unsigned short* __restrict__ Klp,
                    const unsigned short* __restrict__ Vthp, const unsigned short* __restrict__ Vtlp,
                    float* __restrict__ Og, float* __restrict__ Ag) {
  const int tid = (int)threadIdx.x;
  const int l = tid & 63, w = tid >> 6, lm = l & 15, lg = l >> 4;
  const int hd = (int)blockIdx.y;
  const int q0 = (int)blockIdx.x * QB_;
  const int k0 = w * STRIP_;

  __shared__ float SM_[NW_][QB_];
  __shared__ float SS_[NW_][QB_];
  __shared__ __align__(16) float OM[NW_][QB_ * D_];                 // 16 KB
  __shared__ __align__(16) unsigned short Pb[NW_][2][QB_ * PP_];    // 10 KB

  const int maskByte = PRE ? 0 : *flagp;
  const unsigned char* Mb = (const unsigned char*)Mg;
  const int* Mi = (const int*)Mg;

  // ---- Q A-fragments (row = lm, k = lg*8+jj; s=0/1 for k 0..31 / 32..63) ----
  bf16x8 qh[2], ql[2];
  if constexpr (PRE) {
    const unsigned short* qp  = Qhp + ((size_t)hd * LQ_ + q0 + lm) * D_;
    const unsigned short* qp2 = Qlp + ((size_t)hd * LQ_ + q0 + lm) * D_;
    qh[0] = *(const bf16x8*)(qp + lg * 8);       qh[1] = *(const bf16x8*)(qp + 32 + lg * 8);
    ql[0] = *(const bf16x8*)(qp2 + lg * 8);      ql[1] = *(const bf16x8*)(qp2 + 32 + lg * 8);
  } else {
    const float* qp = Qg + ((size_t)hd * LQ_ + q0 + lm) * D_;
#pragma unroll
    for (int s = 0; s < 2; ++s) {
      float x[8];
      *(floatx4*)x       = *(const floatx4*)(qp + s * 32 + lg * 8);
      *(floatx4*)(x + 4) = *(const floatx4*)(qp + s * 32 + lg * 8 + 4);
      hilo8(x, qh[s], ql[s]);
    }
  }

  // =================== QK^T (single pass, scores in registers) ===================
  float s[NTL_][4];
  unsigned wm[4];
  const size_t mwrow = ((size_t)hd * LQ_ + q0 + lg * 4);  // row base for mask words
#pragma unroll
  for (int t = 0; t < NTL_; ++t) {
    if constexpr (PRE) {
      if ((t & 1) == 0) {
#pragma unroll
        for (int j = 0; j < 4; ++j)
          wm[j] = Wp[((mwrow + j) << 6) + (size_t)(w * 16) + (t >> 1)];
      }
    }
    bf16x8 kh[2], kl[2];
    if constexpr (PRE) {
      const unsigned short* kp  = Khp + ((size_t)hd * LK_ + k0 + t * 16 + lm) * D_;
      const unsigned short* kp2 = Klp + ((size_t)hd * LK_ + k0 + t * 16 + lm) * D_;
      kh[0] = *(const bf16x8*)(kp + lg * 8);       kh[1] = *(const bf16x8*)(kp + 32 + lg * 8);
      kl[0] = *(const bf16x8*)(kp2 + lg * 8);      kl[1] = *(const bf16x8*)(kp2 + 32 + lg * 8);
    } else {
      const float* kp = Kg + ((size_t)hd * LK_ + k0 + t * 16 + lm) * D_;
#pragma unroll
      for (int ss = 0; ss < 2; ++ss) {
        float x[8];
        *(floatx4*)x       = *(const floatx4*)(kp + ss * 32 + lg * 8);
        *(floatx4*)(x + 4) = *(const floatx4*)(kp + ss * 32 + lg * 8 + 4);
        hilo8(x, kh[ss], kl[ss]);
      }
    }
    floatx4 acc = {0.f, 0.f, 0.f, 0.f};
#pragma unroll
    for (int ss = 0; ss < 2; ++ss) {
      acc = __builtin_amdgcn_mfma_f32_16x16x32_bf16(qh[ss], kh[ss], acc, 0, 0, 0);
      acc = __builtin_amdgcn_mfma_f32_16x16x32_bf16(ql[ss], kh[ss], acc, 0, 0, 0);
      acc = __builtin_amdgcn_mfma_f32_16x16x32_bf16(qh[ss], kl[ss], acc, 0, 0, 0);
    }
#pragma unroll
    for (int j = 0; j < 4; ++j) {
      int mk;
      if constexpr (PRE) {
        mk = (int)((wm[j] >> ((t & 1) * 16 + lm)) & 1u);
      } else {
        const size_t mi = ((size_t)hd * LQ_ + q0 + lg * 4 + j) * (size_t)LK_ + k0 + t * 16 + lm;
        mk = maskByte ? (int)Mb[mi] : Mi[mi];
      }
      s[t][j] = mk ? -1e30f : acc[j] * 0.125f;
    }
  }

  // =================== softmax stats (1 exp/elem; block merge) ===================
  float mf[4];
#pragma unroll
  for (int j = 0; j < 4; ++j) {
    float m = s[0][j];
#pragma unroll
    for (int t = 1; t < NTL_; ++t) m = fmaxf(m, s[t][j]);
#pragma unroll
    for (int off = 1; off <= 8; off <<= 1) m = fmaxf(m, __shfl_xor(m, off, 64));
    if (lm == 0) SM_[w][lg * 4 + j] = m;
  }
  __syncthreads();
#pragma unroll
  for (int j = 0; j < 4; ++j)
    mf[j] = fmaxf(fmaxf(SM_[0][lg * 4 + j], SM_[1][lg * 4 + j]),
                  fmaxf(SM_[2][lg * 4 + j], SM_[3][lg * 4 + j]));
#pragma unroll
  for (int j = 0; j < 4; ++j) {
    float sum = 0.f;
#pragma unroll
    for (int t = 0; t < NTL_; ++t) {
      float p = __expf(s[t][j] - mf[j]);
      s[t][j] = p;
      sum += p;
    }
#pragma unroll
    for (int off = 1; off <= 8; off <<= 1) sum += __shfl_xor(sum, off, 64);
    if (lm == 0) SS_[w][lg * 4 + j] = sum;
  }
  __syncthreads();
  float inv[4];
#pragma unroll
  for (int j = 0; j < 4; ++j)
    inv[j] = 1.0f / (SS_[0][lg * 4 + j] + SS_[1][lg * 4 + j] +
                     SS_[2][lg * 4 + j] + SS_[3][lg * 4 + j]);

  // =================== PV + attn store (per 32-col chunk) ===================
  floatx4 oacc[4];
#pragma unroll
  for (int n = 0; n < 4; ++n) oacc[n] = {0.f, 0.f, 0.f, 0.f};
  unsigned short* PhL = &Pb[w][0][0];
  unsigned short* PlL = &Pb[w][1][0];

#pragma unroll
  for (int c = 0; c < NCH_; ++c) {
    // pack normalized p (bf16 hi/lo) into per-wave LDS, C-layout -> A-layout bounce
#pragma unroll
    for (int u = 0; u < 2; ++u) {
#pragma unroll
      for (int j = 0; j < 4; ++j) {
        const float p = s[2 * c + u][j] * inv[j];
        const unsigned short hb = f2bf(p);
        const float rem = p - bf2f(hb);
        PhL[(lg * 4 + j) * PP_ + u * 16 + lm] = hb;
        PlL[(lg * 4 + j) * PP_ + u * 16 + lm] =
            (unsigned short)(__builtin_bit_cast(unsigned, rem) >> 16);
      }
    }
    const bf16x8 pa  = *(const bf16x8*)(PhL + lm * PP_ + lg * 8);
    const bf16x8 plo = *(const bf16x8*)(PlL + lm * PP_ + lg * 8);

    // attn store: row = lm, 8 consecutive cols -> full 128B lines per lg-group
    {
      float pr[8];
#pragma unroll
      for (int jj = 0; jj < 8; ++jj)
        pr[jj] = bf2f((unsigned short)pa[jj]) + bf2f((unsigned short)plo[jj]);
      float* arow = Ag + ((size_t)hd * LQ_ + q0 + lm) * (size_t)LK_ + k0 + c * 32 + lg * 8;
      floatx4 v0 = {pr[0], pr[1], pr[2], pr[3]};
      floatx4 v1 = {pr[4], pr[5], pr[6], pr[7]};
      *(floatx4*)arow       = v0;
      *(floatx4*)(arow + 4) = v1;
    }

    // V B-fragments + 3-MFMA accumulate
#pragma unroll
    for (int n = 0; n < 4; ++n) {
      bf16x8 vh, vl;
      if constexpr (PRE) {
        const size_t vo = (size_t)(n * 16 + lm) * LK_ + k0 + c * 32 + lg * 8;
        vh = *(const bf16x8*)(Vthp + vo);
        vl = *(const bf16x8*)(Vtlp + vo);
      } else {
        float vx[8];
#pragma unroll
        for (int jj = 0; jj < 8; ++jj)
          vx[jj] = Vg[(size_t)(k0 + c * 32 + lg * 8 + jj) * D_ + n * 16 + lm];
        hilo8(vx, vh, vl);
      }
      floatx4 o = oacc[n];
      o = __builtin_amdgcn_mfma_f32_16x16x32_bf16(pa,  vh, o, 0, 0, 0);
      o = __builtin_amdgcn_mfma_f32_16x16x32_bf16(plo, vh, o, 0, 0, 0);
      o = __builtin_amdgcn_mfma_f32_16x16x32_bf16(pa,  vl, o, 0, 0, 0);
      oacc[n] = o;
    }
  }

  // =================== k-split O merge ===================
#pragma unroll
  for (int n = 0; n < 4; ++n)
#pragma unroll
    for (int j = 0; j < 4; ++j)
      OM[w][(lg * 4 + j) * D_ + n * 16 + lm] = oacc[n][j];
  __syncthreads();
  for (int i = tid; i < QB_ * D_; i += 256) {
    const float o = OM[0][i] + OM[1][i] + OM[2][i] + OM[3][i];
    Og[((size_t)hd * LQ_ + q0 + (i >> 6)) * D_ + (i & 63)] = o;
  }
}

extern "C" void kernel_launch(void* const* d_in, const int* in_sizes, int n_in,
                              void* d_out, int out_size, void* d_ws, size_t ws_size,
                              hipStream_t stream) {
  const float* Qg = (const float*)d_in[0];
  const float* Kg = (const float*)d_in[1];
  const float* Vg = (const float*)d_in[2];
  const void*  Mg = d_in[3];

  char* ws = (char*)d_ws;
  int* flag = (int*)ws;
  unsigned*       Wp  = (unsigned*)(ws + 16);
  unsigned short* Qhp = (unsigned short*)(ws + 16 + 8388608);
  unsigned short* Qlp = (unsigned short*)(ws + 16 + 8388608 + 4194304);
  unsigned short* Khp = (unsigned short*)(ws + 16 + 8388608 + 2 * 4194304);
  unsigned short* Klp = (unsigned short*)(ws + 16 + 8388608 + 3 * 4194304);
  unsigned short* Vth = (unsigned short*)(ws + 16 + 8388608 + 4 * 4194304);
  unsigned short* Vtl = (unsigned short*)(ws + 16 + 8388608 + 4 * 4194304 + 262144);
  const size_t WS_NEEDED = 16 + 8388608 + 4 * (size_t)4194304 + 2 * (size_t)262144;

  float* Og = (float*)d_out;                                // (H, LQ, DV)
  float* Ag = (float*)d_out + (size_t)H_ * LQ_ * D_;        // (H, LQ, LK)

  hipLaunchKernelGGL(detect_mask_kernel, dim3(1), dim3(64), 0, stream,
                     (const unsigned*)Mg, flag);

  dim3 grid(LQ_ / QB_, H_);
  if (ws_size >= WS_NEEDED) {
    hipLaunchKernelGGL(pack_mask_kernel, dim3(8192), dim3(256), 0, stream, Mg, flag, Wp);
    hipLaunchKernelGGL(conv_hilo_kernel, dim3(1024), dim3(256), 0, stream, Qg, Qhp, Qlp);
    hipLaunchKernelGGL(conv_hilo_kernel, dim3(1024), dim3(256), 0, stream, Kg, Khp, Klp);
    hipLaunchKernelGGL(conv_vt_kernel, dim3(512), dim3(256), 0, stream, Vg, Vth, Vtl);
    hipLaunchKernelGGL((attn_sp_kernel<true>), grid, dim3(256), 0, stream,
                       Qg, Kg, Vg, Mg, flag, Wp, Qhp, Qlp, Khp, Klp, Vth, Vtl, Og, Ag);
  } else {
    hipLaunchKernelGGL((attn_sp_kernel<false>), grid, dim3(256), 0, stream,
                       Qg, Kg, Vg, Mg, flag, Wp, Qhp, Qlp, Khp, Klp, Vth, Vtl, Og, Ag);
  }
}